// Round 8
// baseline (12202.115 us; speedup 1.0000x reference)
//
#include <hip/hip_runtime.h>
#include <math.h>

#define NPT 4096      // points per image (64x64)
#define CCH 512       // channels
#define NB 64         // cholesky panel size
#define NKB 64        // NPT / NB
#define LDB 4160      // RHS leading dim = NPT + 64 feature cols
#define SIGF 0.1f
#define CEPS 1e-6f
#define PI8 25.132741228718345f   // 8*pi

#define APSTR ((size_t)2080 * 4096)   // packed lower-tri Amat floats per batch
#define ILSTR ((size_t)64 * 4096)     // invL floats per batch

typedef __attribute__((ext_vector_type(8))) short bf16x8;
typedef __attribute__((ext_vector_type(4))) float f32x4;
typedef __attribute__((ext_vector_type(4))) unsigned short us4;
typedef unsigned short ushort_t;

__device__ __forceinline__ size_t tbase(int I, int J) {
    return ((size_t)((I * (I + 1) >> 1) + J)) << 12;   // tile (I,J) base, J<=I
}

__device__ inline ushort_t f2bf_rne(float x) {
    unsigned u = __float_as_uint(x);
    unsigned r = u + 0x7FFFu + ((u >> 16) & 1u);
    return (ushort_t)(r >> 16);
}
__device__ inline float bf2f(ushort_t h) { return __uint_as_float(((unsigned)h) << 16); }

__device__ inline void split4(float4 v, us4& h, us4& l) {
    h[0] = f2bf_rne(v.x); l[0] = f2bf_rne(v.x - bf2f(h[0]));
    h[1] = f2bf_rne(v.y); l[1] = f2bf_rne(v.y - bf2f(h[1]));
    h[2] = f2bf_rne(v.z); l[2] = f2bf_rne(v.z - bf2f(h[2]));
    h[3] = f2bf_rne(v.w); l[3] = f2bf_rne(v.w - bf2f(h[3]));
}

// ---------------- norms ----------------
__global__ __launch_bounds__(256) void norms_kernel(const float* __restrict__ X,
                                                    float* __restrict__ nrm, int bofs) {
    int slot = blockIdx.y;
    int p = blockIdx.x * 256 + threadIdx.x;
    const float* Xb = X + (size_t)(slot + bofs) * CCH * NPT;
    float s = 0.f;
    #pragma unroll 8
    for (int ch = 0; ch < CCH; ++ch) {
        float v = Xb[(size_t)ch * NPT + p];
        s += v * v;
    }
    nrm[slot * NPT + p] = sqrtf(s);
}

// ---------------- split: X[b][ch][pt] f32 -> Hi/Lo [pt][ch] bf16 ----------------
__global__ __launch_bounds__(256) void split_kernel(const float* __restrict__ X,
                                                    ushort_t* __restrict__ Hi,
                                                    ushort_t* __restrict__ Lo,
                                                    int bofs) {
    int ch0 = blockIdx.x * 64, pt0 = blockIdx.y * 64;
    const float* Xb = X + (size_t)bofs * CCH * NPT;
    __shared__ float ls[64][65];
    int tid = threadIdx.x;
    for (int t = tid; t < 4096; t += 256) {
        int chl = t >> 6, ptl = t & 63;
        ls[chl][ptl] = Xb[(size_t)(ch0 + chl) * NPT + pt0 + ptl];
    }
    __syncthreads();
    for (int t = tid; t < 4096; t += 256) {
        int ptl = t >> 6, chl = t & 63;
        float v = ls[chl][ptl];
        ushort_t h = f2bf_rne(v);
        float lo = v - bf2f(h);
        Hi[(size_t)(pt0 + ptl) * CCH + ch0 + chl] = h;
        Lo[(size_t)(pt0 + ptl) * CCH + ch0 + chl] = f2bf_rne(lo);
    }
}

// ------------- gramA (K_yy + sigma I) -> packed lower tiles -------------
__global__ __launch_bounds__(256) void gramA_packed_kernel(
    const ushort_t* __restrict__ Yhi, const ushort_t* __restrict__ Ylo,
    const float* __restrict__ nY, float* __restrict__ Cp)
{
    int bx = blockIdx.x, by = blockIdx.y;
    if (bx > by) return;
    int bm = by * 128, bn = bx * 128;

    __shared__ __align__(16) ushort_t Ah[128][40];
    __shared__ __align__(16) ushort_t Al[128][40];
    __shared__ __align__(16) ushort_t Bh[128][40];
    __shared__ __align__(16) ushort_t Bl[128][40];

    int tid = threadIdx.x;
    int lane = tid & 63, wid = tid >> 6;
    int wr = wid >> 1, wc = wid & 1;

    f32x4 acc[4][4];
    #pragma unroll
    for (int i = 0; i < 4; ++i)
        #pragma unroll
        for (int j = 0; j < 4; ++j) acc[i][j] = (f32x4){0.f, 0.f, 0.f, 0.f};

    int arr = tid >> 6;
    int srow = lane >> 2, sc4 = lane & 3;
    const ushort_t* src = (arr == 0 || arr == 2) ? Yhi : Ylo;
    int pbase = (arr < 2) ? bm : bn;
    ushort_t* dst = (arr == 0) ? &Ah[0][0] : (arr == 1) ? &Al[0][0] : (arr == 2) ? &Bh[0][0] : &Bl[0][0];

    for (int k0 = 0; k0 < CCH; k0 += 32) {
        #pragma unroll
        for (int it = 0; it < 8; ++it) {
            int row = it * 16 + srow;
            bf16x8 v = *(const bf16x8*)(src + (size_t)(pbase + row) * CCH + k0 + sc4 * 8);
            *(bf16x8*)(dst + row * 40 + sc4 * 8) = v;
        }
        __syncthreads();
        bf16x8 afh[4], afl[4], bfh[4], bfl[4];
        int kcol = (lane >> 4) * 8;
        #pragma unroll
        for (int mi = 0; mi < 4; ++mi) {
            int r = wr * 64 + mi * 16 + (lane & 15);
            afh[mi] = *(const bf16x8*)&Ah[r][kcol];
            afl[mi] = *(const bf16x8*)&Al[r][kcol];
        }
        #pragma unroll
        for (int nj = 0; nj < 4; ++nj) {
            int r = wc * 64 + nj * 16 + (lane & 15);
            bfh[nj] = *(const bf16x8*)&Bh[r][kcol];
            bfl[nj] = *(const bf16x8*)&Bl[r][kcol];
        }
        #pragma unroll
        for (int mi = 0; mi < 4; ++mi)
            #pragma unroll
            for (int nj = 0; nj < 4; ++nj) {
                acc[mi][nj] = __builtin_amdgcn_mfma_f32_16x16x32_bf16(afh[mi], bfh[nj], acc[mi][nj], 0, 0, 0);
                acc[mi][nj] = __builtin_amdgcn_mfma_f32_16x16x32_bf16(afh[mi], bfl[nj], acc[mi][nj], 0, 0, 0);
                acc[mi][nj] = __builtin_amdgcn_mfma_f32_16x16x32_bf16(afl[mi], bfh[nj], acc[mi][nj], 0, 0, 0);
            }
        __syncthreads();
    }

    int I = (bm >> 6) + wr, J = (bn >> 6) + wc;
    if (J > I) return;
    float* Ct = Cp + tbase(I, J);
    #pragma unroll
    for (int nj = 0; nj < 4; ++nj) {
        int cin = nj * 16 + (lane & 15);
        float nbv = nY[bn + wc * 64 + cin];
        #pragma unroll
        for (int mi = 0; mi < 4; ++mi) {
            f32x4 a = acc[mi][nj];
            #pragma unroll
            for (int q = 0; q < 4; ++q) {
                int rin = mi * 16 + (lane >> 4) * 4 + q;
                float den = nY[bm + wr * 64 + rin] * nbv + CEPS;
                float v = expf(a[q] / den - 1.0f);
                if (I == J && rin == cin) v += SIGF;
                Ct[(rin << 6) + cin] = v;
            }
        }
    }
}

// ------------- gramX (K_yx) -> Brhs row-major -------------
__global__ __launch_bounds__(256) void gramX_kernel(
    const ushort_t* __restrict__ Yhi, const ushort_t* __restrict__ Ylo,
    const float* __restrict__ Xf,
    const float* __restrict__ nY, const float* __restrict__ nX,
    float* __restrict__ Cm)
{
    int bm = blockIdx.y * 128, bn = blockIdx.x * 128;

    __shared__ __align__(16) ushort_t Ah[128][40];
    __shared__ __align__(16) ushort_t Al[128][40];
    __shared__ __align__(16) ushort_t Bh[128][40];
    __shared__ __align__(16) ushort_t Bl[128][40];

    int tid = threadIdx.x;
    int lane = tid & 63, wid = tid >> 6;
    int wr = wid >> 1, wc = wid & 1;

    f32x4 acc[4][4];
    #pragma unroll
    for (int i = 0; i < 4; ++i)
        #pragma unroll
        for (int j = 0; j < 4; ++j) acc[i][j] = (f32x4){0.f, 0.f, 0.f, 0.f};

    int srow = lane >> 2, sc4 = lane & 3;

    for (int k0 = 0; k0 < CCH; k0 += 32) {
        if (tid < 128) {
            const ushort_t* src = (tid < 64) ? Yhi : Ylo;
            ushort_t* dst = (tid < 64) ? &Ah[0][0] : &Al[0][0];
            #pragma unroll
            for (int it = 0; it < 8; ++it) {
                int row = it * 16 + srow;
                bf16x8 v = *(const bf16x8*)(src + (size_t)(bm + row) * CCH + k0 + sc4 * 8);
                *(bf16x8*)(dst + row * 40 + sc4 * 8) = v;
            }
        } else {
            int e0 = (tid - 128) * 8;
            #pragma unroll
            for (int i = 0; i < 8; ++i) {
                int e = e0 + i;
                int ch = e >> 5, p4 = e & 31;
                float4 v = *(const float4*)&Xf[(size_t)(k0 + ch) * NPT + bn + (p4 << 2)];
                us4 h, l;
                split4(v, h, l);
                #pragma unroll
                for (int q = 0; q < 4; ++q) {
                    Bh[(p4 << 2) + q][ch] = h[q];
                    Bl[(p4 << 2) + q][ch] = l[q];
                }
            }
        }
        __syncthreads();
        bf16x8 afh[4], afl[4], bfh[4], bfl[4];
        int kcol = (lane >> 4) * 8;
        #pragma unroll
        for (int mi = 0; mi < 4; ++mi) {
            int r = wr * 64 + mi * 16 + (lane & 15);
            afh[mi] = *(const bf16x8*)&Ah[r][kcol];
            afl[mi] = *(const bf16x8*)&Al[r][kcol];
        }
        #pragma unroll
        for (int nj = 0; nj < 4; ++nj) {
            int r = wc * 64 + nj * 16 + (lane & 15);
            bfh[nj] = *(const bf16x8*)&Bh[r][kcol];
            bfl[nj] = *(const bf16x8*)&Bl[r][kcol];
        }
        #pragma unroll
        for (int mi = 0; mi < 4; ++mi)
            #pragma unroll
            for (int nj = 0; nj < 4; ++nj) {
                acc[mi][nj] = __builtin_amdgcn_mfma_f32_16x16x32_bf16(afh[mi], bfh[nj], acc[mi][nj], 0, 0, 0);
                acc[mi][nj] = __builtin_amdgcn_mfma_f32_16x16x32_bf16(afh[mi], bfl[nj], acc[mi][nj], 0, 0, 0);
                acc[mi][nj] = __builtin_amdgcn_mfma_f32_16x16x32_bf16(afl[mi], bfh[nj], acc[mi][nj], 0, 0, 0);
            }
        __syncthreads();
    }

    #pragma unroll
    for (int nj = 0; nj < 4; ++nj) {
        int col = bn + wc * 64 + nj * 16 + (lane & 15);
        float nbv = nX[col];
        #pragma unroll
        for (int mi = 0; mi < 4; ++mi) {
            f32x4 a = acc[mi][nj];
            #pragma unroll
            for (int q = 0; q < 4; ++q) {
                int row = bm + wr * 64 + mi * 16 + (lane >> 4) * 4 + q;
                float den = nY[row] * nbv + CEPS;
                Cm[(size_t)row * LDB + col] = expf(a[q] / den - 1.0f);
            }
        }
    }
}

// ------------- features -------------
__global__ __launch_bounds__(256) void features_kernel(const float* __restrict__ pw,
                                                       const float* __restrict__ pb,
                                                       float* __restrict__ Brhs) {
    int g = blockIdx.x * 256 + threadIdx.x;
    int q = g >> 6, dd = g & 63;
    int hh = q >> 6, ww = q & 63;
    float gy = -1.0f + (2 * hh + 1) / 64.0f;
    float gx = -1.0f + (2 * ww + 1) / 64.0f;
    float ph = PI8 * (pw[dd * 2 + 0] * gx + pw[dd * 2 + 1] * gy + pb[dd]);
    Brhs[(size_t)q * LDB + NPT + dd] = cosf(ph);
}

// ------------- potf2 on packed diag tile (0,0), z=2 -------------
__global__ __launch_bounds__(256) void potf2_packed_kernel(float* __restrict__ AmatP,
                                                           float* __restrict__ invL, int kb) {
    __shared__ float a[NB][NB + 4];
    __shared__ float iv[NB][NB + 4];
    __shared__ float ddiag[NB];
    int slot = blockIdx.z;
    float* Ab = AmatP + (size_t)slot * APSTR + tbase(kb, kb);
    int tid = threadIdx.x;
    int tx = tid & 15, ty = tid >> 4;
    for (int t = tid; t < NB * NB; t += 256) {
        int i = t >> 6, j = t & 63;
        a[i][j] = Ab[(i << 6) + j];
        iv[i][j] = 0.0f;
    }
    __syncthreads();
    for (int j = 0; j < NB; ++j) {
        float ajj = sqrtf(a[j][j]);
        float dinv = 1.0f / ajj;
        if (tid == 0) ddiag[j] = ajj;
        for (int i = j + 1 + tid; i < NB; i += 256) a[i][j] *= dinv;
        for (int c = tid; c <= j; c += 256)
            iv[j][c] = ((c == j ? 1.0f : 0.0f) - iv[j][c]) * dinv;
        __syncthreads();
        for (int i = j + 1 + ty; i < NB; i += 16) {
            float lij = a[i][j];
            for (int jj = j + 1 + tx; jj < NB; jj += 16)
                a[i][jj] -= lij * a[jj][j];
            for (int c = tx; c <= j; c += 16)
                iv[i][c] += lij * iv[j][c];
        }
        __syncthreads();
    }
    float* iL = invL + (size_t)slot * ILSTR + ((size_t)kb << 12);
    for (int t = tid; t < NB * NB; t += 256) {
        int i = t >> 6, j = t & 63;
        if (j < i)       Ab[(i << 6) + j] = a[i][j];
        else if (j == i) Ab[(i << 6) + j] = ddiag[i];
        iL[t] = (j <= i) ? iv[i][j] : 0.0f;
    }
}

// ------------- fused cholesky step kb: grid(nt, nt, 2), panels stay RAW -------------
// Each block recomputes Pi = Araw[I,kb]*invL[kb]^T (and Pj), updates A[I,J] -= Pi*Pj^T.
// Block (0,0) additionally factors the updated (kb+1,kb+1) tile -> invL[kb+1].
__global__ __launch_bounds__(256) void chol_step_kernel(float* __restrict__ AmatP,
                                                        float* __restrict__ invL, int kb) {
    int bi = blockIdx.y, bj = blockIdx.x;
    if (bj > bi) return;
    int slot = blockIdx.z;
    int I = kb + 1 + bi, J = kb + 1 + bj;
    float* base = AmatP + (size_t)slot * APSTR;
    const float* Ai = base + tbase(I, kb);
    const float* Aj = base + tbase(J, kb);
    float* Ct = base + tbase(I, J);
    const float* iLk = invL + (size_t)slot * ILSTR + ((size_t)kb << 12);

    __shared__ __align__(16) char smem[55296];
    ushort_t (*iLh)[72] = (ushort_t(*)[72])(smem);            // 9216
    ushort_t (*iLl)[72] = (ushort_t(*)[72])(smem + 9216);
    ushort_t (*Pih)[72] = (ushort_t(*)[72])(smem + 18432);    // raw Ai, then Pi split
    ushort_t (*Pil)[72] = (ushort_t(*)[72])(smem + 27648);
    ushort_t (*Pjh)[72] = (ushort_t(*)[72])(smem + 36864);    // raw Aj, then Pj split
    ushort_t (*Pjl)[72] = (ushort_t(*)[72])(smem + 46080);
    // potf2 aliases for block (0,0) (diag => Pj region unused)
    float (*fa)[68]  = (float(*)[68])(smem + 36864);
    float (*fiv)[68] = (float(*)[68])(smem);
    float* fdd = (float*)(smem + 18432);

    int tid = threadIdx.x, lane = tid & 63, w = tid >> 6;
    int frow = lane & 15, fk = (lane >> 4) << 3;
    int diag = (bi == bj);

    for (int e = tid; e < 1024; e += 256) {
        int r = e >> 4, k4 = e & 15;
        us4 h, l;
        float4 v = *(const float4*)&iLk[(r << 6) + (k4 << 2)];
        split4(v, h, l);
        *(us4*)&iLh[r][k4 << 2] = h; *(us4*)&iLl[r][k4 << 2] = l;
        v = *(const float4*)&Ai[(r << 6) + (k4 << 2)];
        split4(v, h, l);
        *(us4*)&Pih[r][k4 << 2] = h; *(us4*)&Pil[r][k4 << 2] = l;
        if (!diag) {
            v = *(const float4*)&Aj[(r << 6) + (k4 << 2)];
            split4(v, h, l);
            *(us4*)&Pjh[r][k4 << 2] = h; *(us4*)&Pjl[r][k4 << 2] = l;
        }
    }
    __syncthreads();

    // trsm: aPi = Ai * iL^T  (and aPj)
    f32x4 aPi[4], aPj[4];
    #pragma unroll
    for (int j = 0; j < 4; ++j) { aPi[j] = (f32x4){0, 0, 0, 0}; aPj[j] = (f32x4){0, 0, 0, 0}; }
    #pragma unroll
    for (int kk0 = 0; kk0 < 64; kk0 += 32) {
        bf16x8 ah = *(const bf16x8*)&Pih[(w << 4) + frow][kk0 + fk];
        bf16x8 al = *(const bf16x8*)&Pil[(w << 4) + frow][kk0 + fk];
        bf16x8 ajh = *(const bf16x8*)&Pjh[(w << 4) + frow][kk0 + fk];
        bf16x8 ajl = *(const bf16x8*)&Pjl[(w << 4) + frow][kk0 + fk];
        #pragma unroll
        for (int nj = 0; nj < 4; ++nj) {
            bf16x8 bh = *(const bf16x8*)&iLh[(nj << 4) + frow][kk0 + fk];
            bf16x8 bl = *(const bf16x8*)&iLl[(nj << 4) + frow][kk0 + fk];
            aPi[nj] = __builtin_amdgcn_mfma_f32_16x16x32_bf16(ah, bh, aPi[nj], 0, 0, 0);
            aPi[nj] = __builtin_amdgcn_mfma_f32_16x16x32_bf16(ah, bl, aPi[nj], 0, 0, 0);
            aPi[nj] = __builtin_amdgcn_mfma_f32_16x16x32_bf16(al, bh, aPi[nj], 0, 0, 0);
            if (!diag) {
                aPj[nj] = __builtin_amdgcn_mfma_f32_16x16x32_bf16(ajh, bh, aPj[nj], 0, 0, 0);
                aPj[nj] = __builtin_amdgcn_mfma_f32_16x16x32_bf16(ajh, bl, aPj[nj], 0, 0, 0);
                aPj[nj] = __builtin_amdgcn_mfma_f32_16x16x32_bf16(ajl, bh, aPj[nj], 0, 0, 0);
            }
        }
    }
    __syncthreads();
    // write Pi (and Pj) split into LDS
    #pragma unroll
    for (int nj = 0; nj < 4; ++nj) {
        int cin = (nj << 4) + frow;
        #pragma unroll
        for (int q = 0; q < 4; ++q) {
            int rin = (w << 4) + ((lane >> 4) << 2) + q;
            float v = aPi[nj][q];
            ushort_t h = f2bf_rne(v);
            Pih[rin][cin] = h; Pil[rin][cin] = f2bf_rne(v - bf2f(h));
            if (!diag) {
                float u = aPj[nj][q];
                ushort_t h2 = f2bf_rne(u);
                Pjh[rin][cin] = h2; Pjl[rin][cin] = f2bf_rne(u - bf2f(h2));
            }
        }
    }
    __syncthreads();

    // syrk: aC = Pi * Pj^T
    const ushort_t (*Bsh)[72] = diag ? Pih : Pjh;
    const ushort_t (*Bsl)[72] = diag ? Pil : Pjl;
    f32x4 aC[4];
    #pragma unroll
    for (int j = 0; j < 4; ++j) aC[j] = (f32x4){0, 0, 0, 0};
    #pragma unroll
    for (int kk0 = 0; kk0 < 64; kk0 += 32) {
        bf16x8 ah = *(const bf16x8*)&Pih[(w << 4) + frow][kk0 + fk];
        bf16x8 al = *(const bf16x8*)&Pil[(w << 4) + frow][kk0 + fk];
        #pragma unroll
        for (int nj = 0; nj < 4; ++nj) {
            bf16x8 bh = *(const bf16x8*)&Bsh[(nj << 4) + frow][kk0 + fk];
            bf16x8 bl = *(const bf16x8*)&Bsl[(nj << 4) + frow][kk0 + fk];
            aC[nj] = __builtin_amdgcn_mfma_f32_16x16x32_bf16(ah, bh, aC[nj], 0, 0, 0);
            aC[nj] = __builtin_amdgcn_mfma_f32_16x16x32_bf16(ah, bl, aC[nj], 0, 0, 0);
            aC[nj] = __builtin_amdgcn_mfma_f32_16x16x32_bf16(al, bh, aC[nj], 0, 0, 0);
        }
    }

    if (!(bi == 0 && bj == 0)) {
        #pragma unroll
        for (int nj = 0; nj < 4; ++nj) {
            int cin = (nj << 4) + frow;
            #pragma unroll
            for (int q = 0; q < 4; ++q) {
                int rin = (w << 4) + ((lane >> 4) << 2) + q;
                Ct[(rin << 6) + cin] -= aC[nj][q];
            }
        }
        return;
    }

    // block (0,0): fused potf2 of updated diag tile (kb+1,kb+1)
    __syncthreads();   // Pi LDS reads done; aliases now safe
    #pragma unroll
    for (int nj = 0; nj < 4; ++nj) {
        int cin = (nj << 4) + frow;
        #pragma unroll
        for (int q = 0; q < 4; ++q) {
            int rin = (w << 4) + ((lane >> 4) << 2) + q;
            fa[rin][cin] = Ct[(rin << 6) + cin] - aC[nj][q];
            fiv[rin][cin] = 0.0f;
        }
    }
    __syncthreads();
    int tx = tid & 15, ty = tid >> 4;
    for (int j = 0; j < NB; ++j) {
        float ajj = sqrtf(fa[j][j]);
        float dinv = 1.0f / ajj;
        if (tid == 0) fdd[j] = ajj;
        for (int i = j + 1 + tid; i < NB; i += 256) fa[i][j] *= dinv;
        for (int c = tid; c <= j; c += 256)
            fiv[j][c] = ((c == j ? 1.0f : 0.0f) - fiv[j][c]) * dinv;
        __syncthreads();
        for (int i = j + 1 + ty; i < NB; i += 16) {
            float lij = fa[i][j];
            for (int jj = j + 1 + tx; jj < NB; jj += 16)
                fa[i][jj] -= lij * fa[jj][j];
            for (int c = tx; c <= j; c += 16)
                fiv[i][c] += lij * fiv[j][c];
        }
        __syncthreads();
    }
    float* iLo = invL + (size_t)slot * ILSTR + ((size_t)(kb + 1) << 12);
    for (int t = tid; t < NB * NB; t += 256) {
        int i = t >> 6, j = t & 63;
        iLo[t] = (j <= i) ? fiv[i][j] : 0.0f;
    }
    (void)fdd;
}

// ------------- prologue: U[0] = invL[0] @ B[0] (f32) -------------
__global__ __launch_bounds__(256) void trsm_rhs_kernel(float* __restrict__ Brhs,
                                                       const float* __restrict__ invL,
                                                       size_t brStride) {
    int slot = blockIdx.z;
    float* Bb = Brhs + (size_t)slot * brStride;
    const float* iL = invL + (size_t)slot * ILSTR;
    int n0 = blockIdx.x * 64;
    __shared__ float invLs[64][68];
    __shared__ float Tds[64][68];
    int tid = threadIdx.x;
    for (int e = tid; e < 1024; e += 256) {
        int r = e >> 4, k4 = e & 15;
        float4 v = *(const float4*)&Bb[(size_t)r * LDB + n0 + (k4 << 2)];
        int c = k4 << 2;
        Tds[r][c] = v.x; Tds[r][c + 1] = v.y; Tds[r][c + 2] = v.z; Tds[r][c + 3] = v.w;
        float4 u = *(const float4*)&iL[(r << 6) + (k4 << 2)];
        invLs[r][c] = u.x; invLs[r][c + 1] = u.y; invLs[r][c + 2] = u.z; invLs[r][c + 3] = u.w;
    }
    __syncthreads();
    int col = tid & 63, rg = tid >> 6;
    #pragma unroll
    for (int i = 0; i < 16; ++i) {
        int r = (i << 2) + rg;
        float s = 0.f;
        #pragma unroll 16
        for (int k = 0; k < 64; ++k) s += invLs[r][k] * Tds[k][col];
        Bb[(size_t)r * LDB + n0 + col] = s;
    }
}

// ------------- solve step kb: grid(65, nt, nz). Panels are RAW; recompute P_L in-block.
//   by>0:  B[I] -= P_L @ U[kb]
//   by==0: U[kb+1] = invL[kb+1] @ (B[I] - P_L @ U[kb]) -------------
__global__ __launch_bounds__(256) void solve_step_kernel(const float* __restrict__ AmatP,
                                                         float* __restrict__ Brhs,
                                                         const float* __restrict__ invL,
                                                         size_t brStride, int kb) {
    int slot = blockIdx.z;
    int n0 = blockIdx.x * 64;
    int I = kb + 1 + blockIdx.y;
    int rb = kb * NB;
    int ri = I * NB;
    const float* Araw = AmatP + (size_t)slot * APSTR + tbase(I, kb);
    const float* iLbase = invL + (size_t)slot * ILSTR;
    float* Bb = Brhs + (size_t)slot * brStride;

    __shared__ __align__(16) char smem[55296];
    ushort_t (*Lh)[72]  = (ushort_t(*)[72])(smem);            // raw A -> later P_L split
    ushort_t (*Ll)[72]  = (ushort_t(*)[72])(smem + 9216);
    ushort_t (*iLh)[72] = (ushort_t(*)[72])(smem + 18432);
    ushort_t (*iLl)[72] = (ushort_t(*)[72])(smem + 27648);
    ushort_t (*Uh)[72]  = (ushort_t(*)[72])(smem + 36864);    // U^T split
    ushort_t (*Ul)[72]  = (ushort_t(*)[72])(smem + 46080);
    float (*invLs)[68] = (float(*)[68])(smem);                // tail aliases
    float (*Tds)[68]   = (float(*)[68])(smem + 18432);

    int tid = threadIdx.x, lane = tid & 63, w = tid >> 6;
    int frow = lane & 15, fk = (lane >> 4) << 3;

    const float* iLk = iLbase + ((size_t)kb << 12);
    for (int e = tid; e < 1024; e += 256) {
        int r = e >> 4, k4 = e & 15;
        us4 h, l;
        float4 v = *(const float4*)&Araw[(r << 6) + (k4 << 2)];
        split4(v, h, l);
        *(us4*)&Lh[r][k4 << 2] = h; *(us4*)&Ll[r][k4 << 2] = l;
        v = *(const float4*)&iLk[(r << 6) + (k4 << 2)];
        split4(v, h, l);
        *(us4*)&iLh[r][k4 << 2] = h; *(us4*)&iLl[r][k4 << 2] = l;
        // U[kb] row r, cols n0+(k4*4..+3) -> transposed [c][k]
        float4 u = *(const float4*)&Bb[(size_t)(rb + r) * LDB + n0 + (k4 << 2)];
        split4(u, h, l);
        #pragma unroll
        for (int q = 0; q < 4; ++q) {
            Uh[(k4 << 2) + q][r] = h[q];
            Ul[(k4 << 2) + q][r] = l[q];
        }
    }
    __syncthreads();

    // P_L = Araw * invL[kb]^T
    f32x4 aP[4];
    #pragma unroll
    for (int j = 0; j < 4; ++j) aP[j] = (f32x4){0, 0, 0, 0};
    #pragma unroll
    for (int kk0 = 0; kk0 < 64; kk0 += 32) {
        bf16x8 ah = *(const bf16x8*)&Lh[(w << 4) + frow][kk0 + fk];
        bf16x8 al = *(const bf16x8*)&Ll[(w << 4) + frow][kk0 + fk];
        #pragma unroll
        for (int nj = 0; nj < 4; ++nj) {
            bf16x8 bh = *(const bf16x8*)&iLh[(nj << 4) + frow][kk0 + fk];
            bf16x8 bl = *(const bf16x8*)&iLl[(nj << 4) + frow][kk0 + fk];
            aP[nj] = __builtin_amdgcn_mfma_f32_16x16x32_bf16(ah, bh, aP[nj], 0, 0, 0);
            aP[nj] = __builtin_amdgcn_mfma_f32_16x16x32_bf16(ah, bl, aP[nj], 0, 0, 0);
            aP[nj] = __builtin_amdgcn_mfma_f32_16x16x32_bf16(al, bh, aP[nj], 0, 0, 0);
        }
    }
    __syncthreads();
    // split P_L back into Lh/Ll
    #pragma unroll
    for (int nj = 0; nj < 4; ++nj) {
        int cin = (nj << 4) + frow;
        #pragma unroll
        for (int q = 0; q < 4; ++q) {
            int rin = (w << 4) + ((lane >> 4) << 2) + q;
            float v = aP[nj][q];
            ushort_t h = f2bf_rne(v);
            Lh[rin][cin] = h; Ll[rin][cin] = f2bf_rne(v - bf2f(h));
        }
    }
    __syncthreads();

    // P = P_L * U[kb]
    f32x4 acc[4];
    #pragma unroll
    for (int j = 0; j < 4; ++j) acc[j] = (f32x4){0, 0, 0, 0};
    #pragma unroll
    for (int kk0 = 0; kk0 < 64; kk0 += 32) {
        bf16x8 ah = *(const bf16x8*)&Lh[(w << 4) + frow][kk0 + fk];
        bf16x8 al = *(const bf16x8*)&Ll[(w << 4) + frow][kk0 + fk];
        #pragma unroll
        for (int nj = 0; nj < 4; ++nj) {
            bf16x8 bh = *(const bf16x8*)&Uh[(nj << 4) + frow][kk0 + fk];
            bf16x8 bl = *(const bf16x8*)&Ul[(nj << 4) + frow][kk0 + fk];
            acc[nj] = __builtin_amdgcn_mfma_f32_16x16x32_bf16(ah, bh, acc[nj], 0, 0, 0);
            acc[nj] = __builtin_amdgcn_mfma_f32_16x16x32_bf16(ah, bl, acc[nj], 0, 0, 0);
            acc[nj] = __builtin_amdgcn_mfma_f32_16x16x32_bf16(al, bh, acc[nj], 0, 0, 0);
        }
    }

    if (blockIdx.y > 0) {
        #pragma unroll
        for (int nj = 0; nj < 4; ++nj) {
            int cin = (nj << 4) + frow;
            #pragma unroll
            for (int q = 0; q < 4; ++q) {
                int rin = (w << 4) + ((lane >> 4) << 2) + q;
                Bb[(size_t)(ri + rin) * LDB + n0 + cin] -= acc[nj][q];
            }
        }
        return;
    }

    // by==0: trsm tail
    __syncthreads();
    #pragma unroll
    for (int nj = 0; nj < 4; ++nj) {
        int cin = (nj << 4) + frow;
        #pragma unroll
        for (int q = 0; q < 4; ++q) {
            int rin = (w << 4) + ((lane >> 4) << 2) + q;
            Tds[rin][cin] = Bb[(size_t)(ri + rin) * LDB + n0 + cin] - acc[nj][q];
        }
    }
    const float* iL2 = iLbase + ((size_t)(kb + 1) << 12);
    for (int e = tid; e < 1024; e += 256) {
        int r = e >> 4, k4 = e & 15;
        float4 u = *(const float4*)&iL2[(r << 6) + (k4 << 2)];
        int c = k4 << 2;
        invLs[r][c] = u.x; invLs[r][c + 1] = u.y; invLs[r][c + 2] = u.z; invLs[r][c + 3] = u.w;
    }
    __syncthreads();
    int col = tid & 63, rg = tid >> 6;
    #pragma unroll
    for (int i = 0; i < 16; ++i) {
        int r = (i << 2) + rg;
        float s = 0.f;
        #pragma unroll 16
        for (int k = 0; k < 64; ++k) s += invLs[r][k] * Tds[k][col];
        Bb[(size_t)(ri + r) * LDB + n0 + col] = s;
    }
}

// ------------- mu -------------
__global__ __launch_bounds__(256) void mu_kernel(const float* __restrict__ Brhs,
                                                 float* __restrict__ out, int bofs) {
    const float* Bb = Brhs;
    int p0 = blockIdx.x * 64;
    __shared__ float Us[16][65];
    __shared__ float Vs[16][65];
    float acc[4][4] = {};
    int tid = threadIdx.x, tx = tid & 15, ty = tid >> 4;
    for (int q0 = 0; q0 < NPT; q0 += 16) {
        for (int t = tid; t < 1024; t += 256) {
            int kk = t >> 6, c = t & 63;
            Us[kk][c] = Bb[(size_t)(q0 + kk) * LDB + p0 + c];
            Vs[kk][c] = Bb[(size_t)(q0 + kk) * LDB + NPT + c];
        }
        __syncthreads();
        #pragma unroll
        for (int kk = 0; kk < 16; ++kk) {
            float uv[4], vv[4];
            #pragma unroll
            for (int i = 0; i < 4; ++i) { uv[i] = Us[kk][ty * 4 + i]; vv[i] = Vs[kk][tx * 4 + i]; }
            #pragma unroll
            for (int i = 0; i < 4; ++i)
                #pragma unroll
                for (int j = 0; j < 4; ++j) acc[i][j] += uv[i] * vv[j];
        }
        __syncthreads();
    }
    #pragma unroll
    for (int i = 0; i < 4; ++i)
        #pragma unroll
        for (int j = 0; j < 4; ++j)
            out[((size_t)bofs * 89 + tx * 4 + j) * NPT + p0 + ty * 4 + i] = acc[i][j];
}

// ------------- kxx_local -------------
__global__ __launch_bounds__(256) void kxx_local_kernel(const float* __restrict__ X,
                                                        const float* __restrict__ nxb,
                                                        float* __restrict__ tmp, int bofs) {
    int r = blockIdx.y;
    int c0 = blockIdx.x * 16;
    const float* Xb = X + (size_t)bofs * CCH * NPT;
    __shared__ float Xs[32][104];
    int tid = threadIdx.x;
    int t0 = tid, t1 = tid + 256;
    int pl0 = t0 / 25, jj0 = t0 % 25;
    int pl1 = t1 / 25, jj1 = t1 % 25;
    int pidx0 = 40 + pl0 + 2;
    int jidx0 = (jj0 / 5) * 20 + pl0 + (jj0 % 5);
    int pidx1 = 40 + pl1 + 2;
    int jidx1 = (jj1 / 5) * 20 + pl1 + (jj1 % 5);
    float acc0 = 0.f, acc1 = 0.f;
    for (int ch0 = 0; ch0 < CCH; ch0 += 32) {
        for (int t = tid; t < 32 * 100; t += 256) {
            int ch = t / 100, i = t % 100;
            int s = i / 20, cc = i % 20;
            int gr = r + s - 2, gc = c0 - 2 + cc;
            float v = 0.f;
            if (gr >= 0 && gr < 64 && gc >= 0 && gc < 64)
                v = Xb[(size_t)(ch0 + ch) * NPT + gr * 64 + gc];
            Xs[ch][i] = v;
        }
        __syncthreads();
        #pragma unroll 8
        for (int kk = 0; kk < 32; ++kk) {
            acc0 += Xs[kk][pidx0] * Xs[kk][jidx0];
            if (t1 < 400) acc1 += Xs[kk][pidx1] * Xs[kk][jidx1];
        }
        __syncthreads();
    }
    {
        int p = r * 64 + c0 + pl0;
        int qr = r + jj0 / 5 - 2, qc = c0 + pl0 + jj0 % 5 - 2;
        float v = 0.f;
        if (qr >= 0 && qr < 64 && qc >= 0 && qc < 64) {
            int q = qr * 64 + qc;
            v = expf(acc0 / (nxb[p] * nxb[q] + CEPS) - 1.0f);
        }
        tmp[(size_t)jj0 * NPT + p] = v;
    }
    if (t1 < 400) {
        int p = r * 64 + c0 + pl1;
        int qr = r + jj1 / 5 - 2, qc = c0 + pl1 + jj1 % 5 - 2;
        float v = 0.f;
        if (qr >= 0 && qr < 64 && qc >= 0 && qc < 64) {
            int q = qr * 64 + qc;
            v = expf(acc1 / (nxb[p] * nxb[q] + CEPS) - 1.0f);
        }
        tmp[(size_t)jj1 * NPT + p] = v;
    }
}

// ------------- cov_local -------------
__global__ __launch_bounds__(256) void cov_local_kernel(const float* __restrict__ Brhs,
                                                        const float* __restrict__ tmp,
                                                        float* __restrict__ out, int bofs) {
    int r = blockIdx.y;
    int c0 = blockIdx.x * 16;
    const float* Ub = Brhs;
    __shared__ float Us[64][104];
    int tid = threadIdx.x;
    int t0 = tid, t1 = tid + 256;
    int pl0 = t0 / 25, jj0 = t0 % 25;
    int pl1 = t1 / 25, jj1 = t1 % 25;
    int pidx0 = 40 + pl0 + 2;
    int jidx0 = (jj0 / 5) * 20 + pl0 + (jj0 % 5);
    int pidx1 = 40 + pl1 + 2;
    int jidx1 = (jj1 / 5) * 20 + pl1 + (jj1 % 5);
    float acc0 = 0.f, acc1 = 0.f;
    for (int q0 = 0; q0 < NPT; q0 += 64) {
        for (int t = tid; t < 64 * 100; t += 256) {
            int qq = t / 100, i = t % 100;
            int s = i / 20, cc = i % 20;
            int gr = r + s - 2, gc = c0 - 2 + cc;
            float v = 0.f;
            if (gr >= 0 && gr < 64 && gc >= 0 && gc < 64)
                v = Ub[(size_t)(q0 + qq) * LDB + gr * 64 + gc];
            Us[qq][i] = v;
        }
        __syncthreads();
        #pragma unroll 8
        for (int kk = 0; kk < 64; ++kk) {
            acc0 += Us[kk][pidx0] * Us[kk][jidx0];
            if (t1 < 400) acc1 += Us[kk][pidx1] * Us[kk][jidx1];
        }
        __syncthreads();
    }
    {
        int p = r * 64 + c0 + pl0;
        int qr = r + jj0 / 5 - 2, qc = c0 + pl0 + jj0 % 5 - 2;
        float v = 0.f;
        if (qr >= 0 && qr < 64 && qc >= 0 && qc < 64)
            v = tmp[(size_t)jj0 * NPT + p] - acc0;
        out[((size_t)bofs * 89 + 64 + jj0) * NPT + p] = v;
    }
    if (t1 < 400) {
        int p = r * 64 + c0 + pl1;
        int qr = r + jj1 / 5 - 2, qc = c0 + pl1 + jj1 % 5 - 2;
        float v = 0.f;
        if (qr >= 0 && qr < 64 && qc >= 0 && qc < 64)
            v = tmp[(size_t)jj1 * NPT + p] - acc1;
        out[((size_t)bofs * 89 + 64 + jj1) * NPT + p] = v;
    }
}

extern "C" void kernel_launch(void* const* d_in, const int* in_sizes, int n_in,
                              void* d_out, int out_size, void* d_ws, size_t ws_size,
                              hipStream_t stream) {
    (void)in_sizes; (void)n_in; (void)out_size;
    const float* x  = (const float*)d_in[0];
    const float* y  = (const float*)d_in[1];
    const float* pw = (const float*)d_in[2];
    const float* pb = (const float*)d_in[3];
    float* out = (float*)d_out;
    float* ws  = (float*)d_ws;

    const size_t SZ_B = (size_t)NPT * LDB;
    const size_t NEED1 = 2 * APSTR + SZ_B + 2 * ILSTR + 4 * NPT + (size_t)NPT * CCH;
    const size_t NEED2 = NEED1 + SZ_B;
    if (ws_size < NEED1 * sizeof(float)) return;
    int twoB = (ws_size >= NEED2 * sizeof(float)) ? 1 : 0;

    float* AmatP = ws;
    float* Brhs  = AmatP + 2 * APSTR;                     // 1 or 2 buffers of SZ_B
    float* invL  = Brhs + (size_t)(twoB ? 2 : 1) * SZ_B;
    float* nx    = invL + 2 * ILSTR;
    float* ny    = nx + 2 * NPT;
    float* ysBuf = ny + 2 * NPT;
    ushort_t* ysH = (ushort_t*)ysBuf;
    ushort_t* ysL = ysH + (size_t)NPT * CCH;
    float* tmp = invL;   // aliased scratch (invL dead when epilogues run / per-batch safe)

    norms_kernel<<<dim3(16, 2), 256, 0, stream>>>(x, nx, 0);
    norms_kernel<<<dim3(16, 2), 256, 0, stream>>>(y, ny, 0);

    // K_yy grams -> packed lower Amat
    for (int b = 0; b < 2; ++b) {
        split_kernel<<<dim3(8, 64, 1), 256, 0, stream>>>(y, ysH, ysL, b);
        gramA_packed_kernel<<<dim3(32, 32, 1), 256, 0, stream>>>(
            ysH, ysL, ny + (size_t)b * NPT, AmatP + (size_t)b * APSTR);
    }

    // fused blocked cholesky, both batches (z=2): panels remain RAW, invL chain built
    potf2_packed_kernel<<<dim3(1, 1, 2), 256, 0, stream>>>(AmatP, invL, 0);
    for (int kb = 0; kb < NKB - 1; ++kb) {
        int nt = NKB - 1 - kb;
        chol_step_kernel<<<dim3(nt, nt, 2), 256, 0, stream>>>(AmatP, invL, kb);
    }

    if (twoB) {
        // both RHS grams, then one z=2 solve chain
        for (int b = 0; b < 2; ++b) {
            split_kernel<<<dim3(8, 64, 1), 256, 0, stream>>>(y, ysH, ysL, b);
            features_kernel<<<dim3(1024, 1), 256, 0, stream>>>(pw, pb, Brhs + (size_t)b * SZ_B);
            gramX_kernel<<<dim3(32, 32, 1), 256, 0, stream>>>(
                ysH, ysL, x + (size_t)b * CCH * NPT, ny + (size_t)b * NPT, nx + (size_t)b * NPT,
                Brhs + (size_t)b * SZ_B);
        }
        trsm_rhs_kernel<<<dim3(65, 1, 2), 256, 0, stream>>>(Brhs, invL, SZ_B);
        for (int kb = 0; kb < NKB - 1; ++kb) {
            solve_step_kernel<<<dim3(65, NKB - 1 - kb, 2), 256, 0, stream>>>(
                AmatP, Brhs, invL, SZ_B, kb);
        }
        for (int b = 0; b < 2; ++b) {
            float* Bb = Brhs + (size_t)b * SZ_B;
            mu_kernel<<<dim3(64, 1, 1), 256, 0, stream>>>(Bb, out, b);
            kxx_local_kernel<<<dim3(4, 64, 1), 256, 0, stream>>>(x, nx + (size_t)b * NPT, tmp, b);
            cov_local_kernel<<<dim3(4, 64, 1), 256, 0, stream>>>(Bb, tmp, out, b);
        }
    } else {
        for (int b = 0; b < 2; ++b) {
            split_kernel<<<dim3(8, 64, 1), 256, 0, stream>>>(y, ysH, ysL, b);
            features_kernel<<<dim3(1024, 1), 256, 0, stream>>>(pw, pb, Brhs);
            gramX_kernel<<<dim3(32, 32, 1), 256, 0, stream>>>(
                ysH, ysL, x + (size_t)b * CCH * NPT, ny + (size_t)b * NPT, nx + (size_t)b * NPT, Brhs);
            trsm_rhs_kernel<<<dim3(65, 1, 1), 256, 0, stream>>>(Brhs, invL + (size_t)b * ILSTR, 0);
            for (int kb = 0; kb < NKB - 1; ++kb) {
                solve_step_kernel<<<dim3(65, NKB - 1 - kb, 1), 256, 0, stream>>>(
                    AmatP + (size_t)b * APSTR, Brhs, invL + (size_t)b * ILSTR, 0, kb);
            }
            mu_kernel<<<dim3(64, 1, 1), 256, 0, stream>>>(Brhs, out, b);
            kxx_local_kernel<<<dim3(4, 64, 1), 256, 0, stream>>>(x, nx + (size_t)b * NPT, tmp, b);
            cov_local_kernel<<<dim3(4, 64, 1), 256, 0, stream>>>(Brhs, tmp, out, b);
        }
    }
}

// Round 9
// 10007.442 us; speedup vs baseline: 1.2193x; 1.2193x over previous
//
#include <hip/hip_runtime.h>
#include <math.h>

#define NPT 4096      // points per image (64x64)
#define CCH 512       // channels
#define NB 64         // cholesky panel size
#define NKB 64        // NPT / NB
#define LDB 4160      // RHS leading dim = NPT + 64 feature cols
#define SIGF 0.1f
#define CEPS 1e-6f
#define PI8 25.132741228718345f   // 8*pi

#define APSTR ((size_t)2080 * 4096)   // packed lower-tri Amat floats per batch
#define ILSTR ((size_t)64 * 4096)     // invL floats per batch

typedef __attribute__((ext_vector_type(8))) short bf16x8;
typedef __attribute__((ext_vector_type(4))) float f32x4;
typedef __attribute__((ext_vector_type(4))) unsigned short us4;
typedef unsigned short ushort_t;

__device__ __forceinline__ size_t tbase(int I, int J) {
    return ((size_t)((I * (I + 1) >> 1) + J)) << 12;   // tile (I,J) base, J<=I
}

__device__ inline ushort_t f2bf_rne(float x) {
    unsigned u = __float_as_uint(x);
    unsigned r = u + 0x7FFFu + ((u >> 16) & 1u);
    return (ushort_t)(r >> 16);
}
__device__ inline float bf2f(ushort_t h) { return __uint_as_float(((unsigned)h) << 16); }

__device__ inline void split4(float4 v, us4& h, us4& l) {
    h[0] = f2bf_rne(v.x); l[0] = f2bf_rne(v.x - bf2f(h[0]));
    h[1] = f2bf_rne(v.y); l[1] = f2bf_rne(v.y - bf2f(h[1]));
    h[2] = f2bf_rne(v.z); l[2] = f2bf_rne(v.z - bf2f(h[2]));
    h[3] = f2bf_rne(v.w); l[3] = f2bf_rne(v.w - bf2f(h[3]));
}

// ---------------- norms ----------------
__global__ __launch_bounds__(256) void norms_kernel(const float* __restrict__ X,
                                                    float* __restrict__ nrm, int bofs) {
    int slot = blockIdx.y;
    int p = blockIdx.x * 256 + threadIdx.x;
    const float* Xb = X + (size_t)(slot + bofs) * CCH * NPT;
    float s = 0.f;
    #pragma unroll 8
    for (int ch = 0; ch < CCH; ++ch) {
        float v = Xb[(size_t)ch * NPT + p];
        s += v * v;
    }
    nrm[slot * NPT + p] = sqrtf(s);
}

// ---------------- split: X[b][ch][pt] f32 -> Hi/Lo [pt][ch] bf16 ----------------
__global__ __launch_bounds__(256) void split_kernel(const float* __restrict__ X,
                                                    ushort_t* __restrict__ Hi,
                                                    ushort_t* __restrict__ Lo,
                                                    int bofs) {
    int ch0 = blockIdx.x * 64, pt0 = blockIdx.y * 64;
    const float* Xb = X + (size_t)bofs * CCH * NPT;
    __shared__ float ls[64][65];
    int tid = threadIdx.x;
    for (int t = tid; t < 4096; t += 256) {
        int chl = t >> 6, ptl = t & 63;
        ls[chl][ptl] = Xb[(size_t)(ch0 + chl) * NPT + pt0 + ptl];
    }
    __syncthreads();
    for (int t = tid; t < 4096; t += 256) {
        int ptl = t >> 6, chl = t & 63;
        float v = ls[chl][ptl];
        ushort_t h = f2bf_rne(v);
        float lo = v - bf2f(h);
        Hi[(size_t)(pt0 + ptl) * CCH + ch0 + chl] = h;
        Lo[(size_t)(pt0 + ptl) * CCH + ch0 + chl] = f2bf_rne(lo);
    }
}

// ------------- gramA (K_yy + sigma I) -> packed lower tiles -------------
__global__ __launch_bounds__(256) void gramA_packed_kernel(
    const ushort_t* __restrict__ Yhi, const ushort_t* __restrict__ Ylo,
    const float* __restrict__ nY, float* __restrict__ Cp)
{
    int bx = blockIdx.x, by = blockIdx.y;
    if (bx > by) return;
    int bm = by * 128, bn = bx * 128;

    __shared__ __align__(16) ushort_t Ah[128][40];
    __shared__ __align__(16) ushort_t Al[128][40];
    __shared__ __align__(16) ushort_t Bh[128][40];
    __shared__ __align__(16) ushort_t Bl[128][40];

    int tid = threadIdx.x;
    int lane = tid & 63, wid = tid >> 6;
    int wr = wid >> 1, wc = wid & 1;

    f32x4 acc[4][4];
    #pragma unroll
    for (int i = 0; i < 4; ++i)
        #pragma unroll
        for (int j = 0; j < 4; ++j) acc[i][j] = (f32x4){0.f, 0.f, 0.f, 0.f};

    int arr = tid >> 6;
    int srow = lane >> 2, sc4 = lane & 3;
    const ushort_t* src = (arr == 0 || arr == 2) ? Yhi : Ylo;
    int pbase = (arr < 2) ? bm : bn;
    ushort_t* dst = (arr == 0) ? &Ah[0][0] : (arr == 1) ? &Al[0][0] : (arr == 2) ? &Bh[0][0] : &Bl[0][0];

    for (int k0 = 0; k0 < CCH; k0 += 32) {
        #pragma unroll
        for (int it = 0; it < 8; ++it) {
            int row = it * 16 + srow;
            bf16x8 v = *(const bf16x8*)(src + (size_t)(pbase + row) * CCH + k0 + sc4 * 8);
            *(bf16x8*)(dst + row * 40 + sc4 * 8) = v;
        }
        __syncthreads();
        bf16x8 afh[4], afl[4], bfh[4], bfl[4];
        int kcol = (lane >> 4) * 8;
        #pragma unroll
        for (int mi = 0; mi < 4; ++mi) {
            int r = wr * 64 + mi * 16 + (lane & 15);
            afh[mi] = *(const bf16x8*)&Ah[r][kcol];
            afl[mi] = *(const bf16x8*)&Al[r][kcol];
        }
        #pragma unroll
        for (int nj = 0; nj < 4; ++nj) {
            int r = wc * 64 + nj * 16 + (lane & 15);
            bfh[nj] = *(const bf16x8*)&Bh[r][kcol];
            bfl[nj] = *(const bf16x8*)&Bl[r][kcol];
        }
        #pragma unroll
        for (int mi = 0; mi < 4; ++mi)
            #pragma unroll
            for (int nj = 0; nj < 4; ++nj) {
                acc[mi][nj] = __builtin_amdgcn_mfma_f32_16x16x32_bf16(afh[mi], bfh[nj], acc[mi][nj], 0, 0, 0);
                acc[mi][nj] = __builtin_amdgcn_mfma_f32_16x16x32_bf16(afh[mi], bfl[nj], acc[mi][nj], 0, 0, 0);
                acc[mi][nj] = __builtin_amdgcn_mfma_f32_16x16x32_bf16(afl[mi], bfh[nj], acc[mi][nj], 0, 0, 0);
            }
        __syncthreads();
    }

    int I = (bm >> 6) + wr, J = (bn >> 6) + wc;
    if (J > I) return;
    float* Ct = Cp + tbase(I, J);
    #pragma unroll
    for (int nj = 0; nj < 4; ++nj) {
        int cin = nj * 16 + (lane & 15);
        float nbv = nY[bn + wc * 64 + cin];
        #pragma unroll
        for (int mi = 0; mi < 4; ++mi) {
            f32x4 a = acc[mi][nj];
            #pragma unroll
            for (int q = 0; q < 4; ++q) {
                int rin = mi * 16 + (lane >> 4) * 4 + q;
                float den = nY[bm + wr * 64 + rin] * nbv + CEPS;
                float v = expf(a[q] / den - 1.0f);
                if (I == J && rin == cin) v += SIGF;
                Ct[(rin << 6) + cin] = v;
            }
        }
    }
}

// ------------- gramX (K_yx) -> Brhs row-major -------------
__global__ __launch_bounds__(256) void gramX_kernel(
    const ushort_t* __restrict__ Yhi, const ushort_t* __restrict__ Ylo,
    const float* __restrict__ Xf,
    const float* __restrict__ nY, const float* __restrict__ nX,
    float* __restrict__ Cm)
{
    int bm = blockIdx.y * 128, bn = blockIdx.x * 128;

    __shared__ __align__(16) ushort_t Ah[128][40];
    __shared__ __align__(16) ushort_t Al[128][40];
    __shared__ __align__(16) ushort_t Bh[128][40];
    __shared__ __align__(16) ushort_t Bl[128][40];

    int tid = threadIdx.x;
    int lane = tid & 63, wid = tid >> 6;
    int wr = wid >> 1, wc = wid & 1;

    f32x4 acc[4][4];
    #pragma unroll
    for (int i = 0; i < 4; ++i)
        #pragma unroll
        for (int j = 0; j < 4; ++j) acc[i][j] = (f32x4){0.f, 0.f, 0.f, 0.f};

    int srow = lane >> 2, sc4 = lane & 3;

    for (int k0 = 0; k0 < CCH; k0 += 32) {
        if (tid < 128) {
            const ushort_t* src = (tid < 64) ? Yhi : Ylo;
            ushort_t* dst = (tid < 64) ? &Ah[0][0] : &Al[0][0];
            #pragma unroll
            for (int it = 0; it < 8; ++it) {
                int row = it * 16 + srow;
                bf16x8 v = *(const bf16x8*)(src + (size_t)(bm + row) * CCH + k0 + sc4 * 8);
                *(bf16x8*)(dst + row * 40 + sc4 * 8) = v;
            }
        } else {
            int e0 = (tid - 128) * 8;
            #pragma unroll
            for (int i = 0; i < 8; ++i) {
                int e = e0 + i;
                int ch = e >> 5, p4 = e & 31;
                float4 v = *(const float4*)&Xf[(size_t)(k0 + ch) * NPT + bn + (p4 << 2)];
                us4 h, l;
                split4(v, h, l);
                #pragma unroll
                for (int q = 0; q < 4; ++q) {
                    Bh[(p4 << 2) + q][ch] = h[q];
                    Bl[(p4 << 2) + q][ch] = l[q];
                }
            }
        }
        __syncthreads();
        bf16x8 afh[4], afl[4], bfh[4], bfl[4];
        int kcol = (lane >> 4) * 8;
        #pragma unroll
        for (int mi = 0; mi < 4; ++mi) {
            int r = wr * 64 + mi * 16 + (lane & 15);
            afh[mi] = *(const bf16x8*)&Ah[r][kcol];
            afl[mi] = *(const bf16x8*)&Al[r][kcol];
        }
        #pragma unroll
        for (int nj = 0; nj < 4; ++nj) {
            int r = wc * 64 + nj * 16 + (lane & 15);
            bfh[nj] = *(const bf16x8*)&Bh[r][kcol];
            bfl[nj] = *(const bf16x8*)&Bl[r][kcol];
        }
        #pragma unroll
        for (int mi = 0; mi < 4; ++mi)
            #pragma unroll
            for (int nj = 0; nj < 4; ++nj) {
                acc[mi][nj] = __builtin_amdgcn_mfma_f32_16x16x32_bf16(afh[mi], bfh[nj], acc[mi][nj], 0, 0, 0);
                acc[mi][nj] = __builtin_amdgcn_mfma_f32_16x16x32_bf16(afh[mi], bfl[nj], acc[mi][nj], 0, 0, 0);
                acc[mi][nj] = __builtin_amdgcn_mfma_f32_16x16x32_bf16(afl[mi], bfh[nj], acc[mi][nj], 0, 0, 0);
            }
        __syncthreads();
    }

    #pragma unroll
    for (int nj = 0; nj < 4; ++nj) {
        int col = bn + wc * 64 + nj * 16 + (lane & 15);
        float nbv = nX[col];
        #pragma unroll
        for (int mi = 0; mi < 4; ++mi) {
            f32x4 a = acc[mi][nj];
            #pragma unroll
            for (int q = 0; q < 4; ++q) {
                int row = bm + wr * 64 + mi * 16 + (lane >> 4) * 4 + q;
                float den = nY[row] * nbv + CEPS;
                Cm[(size_t)row * LDB + col] = expf(a[q] / den - 1.0f);
            }
        }
    }
}

// ------------- features -------------
__global__ __launch_bounds__(256) void features_kernel(const float* __restrict__ pw,
                                                       const float* __restrict__ pb,
                                                       float* __restrict__ Brhs) {
    int g = blockIdx.x * 256 + threadIdx.x;
    int q = g >> 6, dd = g & 63;
    int hh = q >> 6, ww = q & 63;
    float gy = -1.0f + (2 * hh + 1) / 64.0f;
    float gx = -1.0f + (2 * ww + 1) / 64.0f;
    float ph = PI8 * (pw[dd * 2 + 0] * gx + pw[dd * 2 + 1] * gy + pb[dd]);
    Brhs[(size_t)q * LDB + NPT + dd] = cosf(ph);
}

// ------------- potf2 on packed diag tile (kb,kb), z=2 -------------
__global__ __launch_bounds__(256) void potf2_packed_kernel(float* __restrict__ AmatP,
                                                           float* __restrict__ invL, int kb) {
    __shared__ float a[NB][NB + 4];
    __shared__ float iv[NB][NB + 4];
    __shared__ float ddiag[NB];
    int slot = blockIdx.z;
    float* Ab = AmatP + (size_t)slot * APSTR + tbase(kb, kb);
    int tid = threadIdx.x;
    int tx = tid & 15, ty = tid >> 4;
    for (int t = tid; t < NB * NB; t += 256) {
        int i = t >> 6, j = t & 63;
        a[i][j] = Ab[(i << 6) + j];
        iv[i][j] = 0.0f;
    }
    __syncthreads();
    for (int j = 0; j < NB; ++j) {
        float ajj = sqrtf(a[j][j]);
        float dinv = 1.0f / ajj;
        if (tid == 0) ddiag[j] = ajj;
        for (int i = j + 1 + tid; i < NB; i += 256) a[i][j] *= dinv;
        for (int c = tid; c <= j; c += 256)
            iv[j][c] = ((c == j ? 1.0f : 0.0f) - iv[j][c]) * dinv;
        __syncthreads();
        for (int i = j + 1 + ty; i < NB; i += 16) {
            float lij = a[i][j];
            for (int jj = j + 1 + tx; jj < NB; jj += 16)
                a[i][jj] -= lij * a[jj][j];
            for (int c = tx; c <= j; c += 16)
                iv[i][c] += lij * iv[j][c];
        }
        __syncthreads();
    }
    float* iL = invL + (size_t)slot * ILSTR + ((size_t)kb << 12);
    for (int t = tid; t < NB * NB; t += 256) {
        int i = t >> 6, j = t & 63;
        if (j < i)       Ab[(i << 6) + j] = a[i][j];
        else if (j == i) Ab[(i << 6) + j] = ddiag[i];
        iL[t] = (j <= i) ? iv[i][j] : 0.0f;
    }
}

// ------------- trsm on packed tile (I,kb): T = T @ invL^T, z=2 -------------
__global__ __launch_bounds__(256) void trsm_packed_kernel(float* __restrict__ AmatP,
                                                          const float* __restrict__ invL, int kb) {
    int slot = blockIdx.z;
    int I = kb + 1 + blockIdx.x;
    float* At = AmatP + (size_t)slot * APSTR + tbase(I, kb);
    const float* iL = invL + (size_t)slot * ILSTR + ((size_t)kb << 12);

    __shared__ __align__(16) ushort_t Aoh[64][72], Aol[64][72];
    __shared__ __align__(16) ushort_t Bh[64][72], Bl[64][72];

    int tid = threadIdx.x, lane = tid & 63, w = tid >> 6;
    int frow = lane & 15, fk = (lane >> 4) << 3;
    f32x4 acc[4];
    #pragma unroll
    for (int j = 0; j < 4; ++j) acc[j] = (f32x4){0, 0, 0, 0};

    for (int e = tid; e < 1024; e += 256) {
        int r = e >> 4, k4 = e & 15;
        us4 h, l;
        float4 v = *(const float4*)&At[(r << 6) + (k4 << 2)];
        split4(v, h, l);
        *(us4*)&Aoh[r][k4 << 2] = h; *(us4*)&Aol[r][k4 << 2] = l;
        float4 u = *(const float4*)&iL[(r << 6) + (k4 << 2)];
        split4(u, h, l);
        *(us4*)&Bh[r][k4 << 2] = h; *(us4*)&Bl[r][k4 << 2] = l;
    }
    __syncthreads();
    #pragma unroll
    for (int kk0 = 0; kk0 < 64; kk0 += 32) {
        bf16x8 ah = *(const bf16x8*)&Aoh[(w << 4) + frow][kk0 + fk];
        bf16x8 al = *(const bf16x8*)&Aol[(w << 4) + frow][kk0 + fk];
        #pragma unroll
        for (int nj = 0; nj < 4; ++nj) {
            bf16x8 bh = *(const bf16x8*)&Bh[(nj << 4) + frow][kk0 + fk];
            bf16x8 bl = *(const bf16x8*)&Bl[(nj << 4) + frow][kk0 + fk];
            acc[nj] = __builtin_amdgcn_mfma_f32_16x16x32_bf16(ah, bh, acc[nj], 0, 0, 0);
            acc[nj] = __builtin_amdgcn_mfma_f32_16x16x32_bf16(ah, bl, acc[nj], 0, 0, 0);
            acc[nj] = __builtin_amdgcn_mfma_f32_16x16x32_bf16(al, bh, acc[nj], 0, 0, 0);
        }
    }
    #pragma unroll
    for (int nj = 0; nj < 4; ++nj)
        #pragma unroll
        for (int q = 0; q < 4; ++q) {
            int rin = (w << 4) + ((lane >> 4) << 2) + q;
            At[(rin << 6) + (nj << 4) + frow] = acc[nj][q];
        }
}

// ------------- syrk on packed tiles + fused potf2 of next diag, z=2 -------------
__global__ __launch_bounds__(256) void syrk_fact_packed_kernel(float* __restrict__ AmatP,
                                                               float* __restrict__ invL, int kb) {
    int bi = blockIdx.y, bj = blockIdx.x;
    if (bj > bi) return;
    int slot = blockIdx.z;
    int I = kb + 1 + bi, J = kb + 1 + bj;
    float* base = AmatP + (size_t)slot * APSTR;
    const float* Pi_t = base + tbase(I, kb);
    const float* Pj_t = base + tbase(J, kb);
    float* Ct = base + tbase(I, J);

    __shared__ __align__(16) char smem[36864];
    ushort_t (*Pih)[72] = (ushort_t(*)[72])(smem);
    ushort_t (*Pil)[72] = (ushort_t(*)[72])(smem + 9216);
    ushort_t (*Pjh)[72] = (ushort_t(*)[72])(smem + 18432);
    ushort_t (*Pjl)[72] = (ushort_t(*)[72])(smem + 27648);
    float (*fa)[68] = (float(*)[68])(smem);
    float (*fiv)[68] = (float(*)[68])(smem + 17408);
    float* fdd = (float*)(smem + 34816);

    int tid = threadIdx.x, lane = tid & 63, w = tid >> 6;
    int frow = lane & 15, fk = (lane >> 4) << 3;
    f32x4 acc[4];
    #pragma unroll
    for (int j = 0; j < 4; ++j) acc[j] = (f32x4){0, 0, 0, 0};

    for (int e = tid; e < 1024; e += 256) {
        int r = e >> 4, k4 = e & 15;
        us4 h, l;
        float4 v = *(const float4*)&Pi_t[(r << 6) + (k4 << 2)];
        split4(v, h, l);
        *(us4*)&Pih[r][k4 << 2] = h; *(us4*)&Pil[r][k4 << 2] = l;
        float4 u = *(const float4*)&Pj_t[(r << 6) + (k4 << 2)];
        split4(u, h, l);
        *(us4*)&Pjh[r][k4 << 2] = h; *(us4*)&Pjl[r][k4 << 2] = l;
    }
    __syncthreads();
    #pragma unroll
    for (int kk0 = 0; kk0 < 64; kk0 += 32) {
        bf16x8 ah = *(const bf16x8*)&Pih[(w << 4) + frow][kk0 + fk];
        bf16x8 al = *(const bf16x8*)&Pil[(w << 4) + frow][kk0 + fk];
        #pragma unroll
        for (int nj = 0; nj < 4; ++nj) {
            bf16x8 bh = *(const bf16x8*)&Pjh[(nj << 4) + frow][kk0 + fk];
            bf16x8 bl = *(const bf16x8*)&Pjl[(nj << 4) + frow][kk0 + fk];
            acc[nj] = __builtin_amdgcn_mfma_f32_16x16x32_bf16(ah, bh, acc[nj], 0, 0, 0);
            acc[nj] = __builtin_amdgcn_mfma_f32_16x16x32_bf16(ah, bl, acc[nj], 0, 0, 0);
            acc[nj] = __builtin_amdgcn_mfma_f32_16x16x32_bf16(al, bh, acc[nj], 0, 0, 0);
        }
    }

    if (!(bi == 0 && bj == 0)) {
        #pragma unroll
        for (int nj = 0; nj < 4; ++nj) {
            int cin = (nj << 4) + frow;
            #pragma unroll
            for (int q = 0; q < 4; ++q) {
                int rin = (w << 4) + ((lane >> 4) << 2) + q;
                Ct[(rin << 6) + cin] -= acc[nj][q];
            }
        }
        return;
    }

    __syncthreads();
    #pragma unroll
    for (int nj = 0; nj < 4; ++nj) {
        int cin = (nj << 4) + frow;
        #pragma unroll
        for (int q = 0; q < 4; ++q) {
            int rin = (w << 4) + ((lane >> 4) << 2) + q;
            fa[rin][cin] = Ct[(rin << 6) + cin] - acc[nj][q];
            fiv[rin][cin] = 0.0f;
        }
    }
    __syncthreads();
    int tx = tid & 15, ty = tid >> 4;
    for (int j = 0; j < NB; ++j) {
        float ajj = sqrtf(fa[j][j]);
        float dinv = 1.0f / ajj;
        if (tid == 0) fdd[j] = ajj;
        for (int i = j + 1 + tid; i < NB; i += 256) fa[i][j] *= dinv;
        for (int c = tid; c <= j; c += 256)
            fiv[j][c] = ((c == j ? 1.0f : 0.0f) - fiv[j][c]) * dinv;
        __syncthreads();
        for (int i = j + 1 + ty; i < NB; i += 16) {
            float lij = fa[i][j];
            for (int jj = j + 1 + tx; jj < NB; jj += 16)
                fa[i][jj] -= lij * fa[jj][j];
            for (int c = tx; c <= j; c += 16)
                fiv[i][c] += lij * fiv[j][c];
        }
        __syncthreads();
    }
    float* iL = invL + (size_t)slot * ILSTR + ((size_t)(kb + 1) << 12);
    for (int t = tid; t < NB * NB; t += 256) {
        int i = t >> 6, j = t & 63;
        if (j < i)       Ct[(i << 6) + j] = fa[i][j];
        else if (j == i) Ct[(i << 6) + j] = fdd[i];
        iL[t] = (j <= i) ? fiv[i][j] : 0.0f;
    }
}

// ------------- prologue: U[0] = invL[0] @ B[0] (f32) -------------
__global__ __launch_bounds__(256) void trsm_rhs_kernel(float* __restrict__ Brhs,
                                                       const float* __restrict__ invL,
                                                       size_t brStride) {
    int slot = blockIdx.z;
    float* Bb = Brhs + (size_t)slot * brStride;
    const float* iL = invL + (size_t)slot * ILSTR;
    int n0 = blockIdx.x * 64;
    __shared__ float invLs[64][68];
    __shared__ float Tds[64][68];
    int tid = threadIdx.x;
    for (int e = tid; e < 1024; e += 256) {
        int r = e >> 4, k4 = e & 15;
        float4 v = *(const float4*)&Bb[(size_t)r * LDB + n0 + (k4 << 2)];
        int c = k4 << 2;
        Tds[r][c] = v.x; Tds[r][c + 1] = v.y; Tds[r][c + 2] = v.z; Tds[r][c + 3] = v.w;
        float4 u = *(const float4*)&iL[(r << 6) + (k4 << 2)];
        invLs[r][c] = u.x; invLs[r][c + 1] = u.y; invLs[r][c + 2] = u.z; invLs[r][c + 3] = u.w;
    }
    __syncthreads();
    int col = tid & 63, rg = tid >> 6;
    #pragma unroll
    for (int i = 0; i < 16; ++i) {
        int r = (i << 2) + rg;
        float s = 0.f;
        #pragma unroll 16
        for (int k = 0; k < 64; ++k) s += invLs[r][k] * Tds[k][col];
        Bb[(size_t)r * LDB + n0 + col] = s;
    }
}

// ------------- solve step kb (round-7 body + batch stride): trsm'd panels -------------
__global__ __launch_bounds__(256) void solve_step_kernel(const float* __restrict__ AmatP,
                                                         float* __restrict__ Brhs,
                                                         const float* __restrict__ invL,
                                                         size_t brStride, int kb) {
    int slot = blockIdx.z;
    int n0 = blockIdx.x * 64;
    int I = kb + 1 + blockIdx.y;
    int rb = kb * NB;
    int ri = I * NB;
    const float* Lt = AmatP + (size_t)slot * APSTR + tbase(I, kb);
    const float* iLbase = invL + (size_t)slot * ILSTR;
    float* Bb = Brhs + (size_t)slot * brStride;

    __shared__ __align__(16) char smem[36864];
    ushort_t (*Lh)[72] = (ushort_t(*)[72])(smem);             // 9216
    ushort_t (*Ll)[72] = (ushort_t(*)[72])(smem + 9216);
    ushort_t (*Uh)[72] = (ushort_t(*)[72])(smem + 18432);     // [c][k] transposed
    ushort_t (*Ul)[72] = (ushort_t(*)[72])(smem + 27648);
    float (*invLs)[68] = (float(*)[68])(smem);                // tail aliases
    float (*Tds)[68]   = (float(*)[68])(smem + 18432);

    int tid = threadIdx.x, lane = tid & 63, w = tid >> 6;
    int frow = lane & 15, fk = (lane >> 4) << 3;

    for (int e = tid; e < 1024; e += 256) {
        int r = e >> 4, k4 = e & 15;
        us4 h, l;
        float4 v = *(const float4*)&Lt[(r << 6) + (k4 << 2)];
        split4(v, h, l);
        *(us4*)&Lh[r][k4 << 2] = h; *(us4*)&Ll[r][k4 << 2] = l;
        float4 u = *(const float4*)&Bb[(size_t)(rb + r) * LDB + n0 + (k4 << 2)];
        split4(u, h, l);
        #pragma unroll
        for (int q = 0; q < 4; ++q) {
            Uh[(k4 << 2) + q][r] = h[q];
            Ul[(k4 << 2) + q][r] = l[q];
        }
    }
    __syncthreads();

    f32x4 acc[4];
    #pragma unroll
    for (int j = 0; j < 4; ++j) acc[j] = (f32x4){0, 0, 0, 0};
    #pragma unroll
    for (int kk0 = 0; kk0 < 64; kk0 += 32) {
        bf16x8 ah = *(const bf16x8*)&Lh[(w << 4) + frow][kk0 + fk];
        bf16x8 al = *(const bf16x8*)&Ll[(w << 4) + frow][kk0 + fk];
        #pragma unroll
        for (int nj = 0; nj < 4; ++nj) {
            bf16x8 bh = *(const bf16x8*)&Uh[(nj << 4) + frow][kk0 + fk];
            bf16x8 bl = *(const bf16x8*)&Ul[(nj << 4) + frow][kk0 + fk];
            acc[nj] = __builtin_amdgcn_mfma_f32_16x16x32_bf16(ah, bh, acc[nj], 0, 0, 0);
            acc[nj] = __builtin_amdgcn_mfma_f32_16x16x32_bf16(ah, bl, acc[nj], 0, 0, 0);
            acc[nj] = __builtin_amdgcn_mfma_f32_16x16x32_bf16(al, bh, acc[nj], 0, 0, 0);
        }
    }

    if (blockIdx.y > 0) {
        #pragma unroll
        for (int nj = 0; nj < 4; ++nj) {
            int cin = (nj << 4) + frow;
            #pragma unroll
            for (int q = 0; q < 4; ++q) {
                int rin = (w << 4) + ((lane >> 4) << 2) + q;
                Bb[(size_t)(ri + rin) * LDB + n0 + cin] -= acc[nj][q];
            }
        }
        return;
    }

    // by==0: trsm tail
    __syncthreads();
    #pragma unroll
    for (int nj = 0; nj < 4; ++nj) {
        int cin = (nj << 4) + frow;
        #pragma unroll
        for (int q = 0; q < 4; ++q) {
            int rin = (w << 4) + ((lane >> 4) << 2) + q;
            Tds[rin][cin] = Bb[(size_t)(ri + rin) * LDB + n0 + cin] - acc[nj][q];
        }
    }
    const float* iL2 = iLbase + ((size_t)(kb + 1) << 12);
    for (int e = tid; e < 1024; e += 256) {
        int r = e >> 4, k4 = e & 15;
        float4 u = *(const float4*)&iL2[(r << 6) + (k4 << 2)];
        int c = k4 << 2;
        invLs[r][c] = u.x; invLs[r][c + 1] = u.y; invLs[r][c + 2] = u.z; invLs[r][c + 3] = u.w;
    }
    __syncthreads();
    int col = tid & 63, rg = tid >> 6;
    #pragma unroll
    for (int i = 0; i < 16; ++i) {
        int r = (i << 2) + rg;
        float s = 0.f;
        #pragma unroll 16
        for (int k = 0; k < 64; ++k) s += invLs[r][k] * Tds[k][col];
        Bb[(size_t)(ri + r) * LDB + n0 + col] = s;
    }
}

// ------------- mu -------------
__global__ __launch_bounds__(256) void mu_kernel(const float* __restrict__ Brhs,
                                                 float* __restrict__ out, int bofs) {
    const float* Bb = Brhs;
    int p0 = blockIdx.x * 64;
    __shared__ float Us[16][65];
    __shared__ float Vs[16][65];
    float acc[4][4] = {};
    int tid = threadIdx.x, tx = tid & 15, ty = tid >> 4;
    for (int q0 = 0; q0 < NPT; q0 += 16) {
        for (int t = tid; t < 1024; t += 256) {
            int kk = t >> 6, c = t & 63;
            Us[kk][c] = Bb[(size_t)(q0 + kk) * LDB + p0 + c];
            Vs[kk][c] = Bb[(size_t)(q0 + kk) * LDB + NPT + c];
        }
        __syncthreads();
        #pragma unroll
        for (int kk = 0; kk < 16; ++kk) {
            float uv[4], vv[4];
            #pragma unroll
            for (int i = 0; i < 4; ++i) { uv[i] = Us[kk][ty * 4 + i]; vv[i] = Vs[kk][tx * 4 + i]; }
            #pragma unroll
            for (int i = 0; i < 4; ++i)
                #pragma unroll
                for (int j = 0; j < 4; ++j) acc[i][j] += uv[i] * vv[j];
        }
        __syncthreads();
    }
    #pragma unroll
    for (int i = 0; i < 4; ++i)
        #pragma unroll
        for (int j = 0; j < 4; ++j)
            out[((size_t)bofs * 89 + tx * 4 + j) * NPT + p0 + ty * 4 + i] = acc[i][j];
}

// ------------- zero fill -------------
__global__ __launch_bounds__(256) void zero_kernel(float* __restrict__ p, int n) {
    int i = blockIdx.x * 256 + threadIdx.x;
    if (i < n) p[i] = 0.0f;
}

// ------------- kxx_local (writes tmpX) -------------
__global__ __launch_bounds__(256) void kxx_local_kernel(const float* __restrict__ X,
                                                        const float* __restrict__ nxb,
                                                        float* __restrict__ tmp, int bofs) {
    int r = blockIdx.y;
    int c0 = blockIdx.x * 16;
    const float* Xb = X + (size_t)bofs * CCH * NPT;
    __shared__ float Xs[32][104];
    int tid = threadIdx.x;
    int t0 = tid, t1 = tid + 256;
    int pl0 = t0 / 25, jj0 = t0 % 25;
    int pl1 = t1 / 25, jj1 = t1 % 25;
    int pidx0 = 40 + pl0 + 2;
    int jidx0 = (jj0 / 5) * 20 + pl0 + (jj0 % 5);
    int pidx1 = 40 + pl1 + 2;
    int jidx1 = (jj1 / 5) * 20 + pl1 + (jj1 % 5);
    float acc0 = 0.f, acc1 = 0.f;
    for (int ch0 = 0; ch0 < CCH; ch0 += 32) {
        for (int t = tid; t < 32 * 100; t += 256) {
            int ch = t / 100, i = t % 100;
            int s = i / 20, cc = i % 20;
            int gr = r + s - 2, gc = c0 - 2 + cc;
            float v = 0.f;
            if (gr >= 0 && gr < 64 && gc >= 0 && gc < 64)
                v = Xb[(size_t)(ch0 + ch) * NPT + gr * 64 + gc];
            Xs[ch][i] = v;
        }
        __syncthreads();
        #pragma unroll 8
        for (int kk = 0; kk < 32; ++kk) {
            acc0 += Xs[kk][pidx0] * Xs[kk][jidx0];
            if (t1 < 400) acc1 += Xs[kk][pidx1] * Xs[kk][jidx1];
        }
        __syncthreads();
    }
    {
        int p = r * 64 + c0 + pl0;
        int qr = r + jj0 / 5 - 2, qc = c0 + pl0 + jj0 % 5 - 2;
        float v = 0.f;
        if (qr >= 0 && qr < 64 && qc >= 0 && qc < 64) {
            int q = qr * 64 + qc;
            v = expf(acc0 / (nxb[p] * nxb[q] + CEPS) - 1.0f);
        }
        tmp[(size_t)jj0 * NPT + p] = v;
    }
    if (t1 < 400) {
        int p = r * 64 + c0 + pl1;
        int qr = r + jj1 / 5 - 2, qc = c0 + pl1 + jj1 % 5 - 2;
        float v = 0.f;
        if (qr >= 0 && qr < 64 && qc >= 0 && qc < 64) {
            int q = qr * 64 + qc;
            v = expf(acc1 / (nxb[p] * nxb[q] + CEPS) - 1.0f);
        }
        tmp[(size_t)jj1 * NPT + p] = v;
    }
}

// ------------- cov_part: k-split 8-way, partial dot -> atomicAdd into covAcc -------------
__global__ __launch_bounds__(256) void cov_part_kernel(const float* __restrict__ Brhs,
                                                       float* __restrict__ covAcc) {
    int r = blockIdx.y;
    int c0 = blockIdx.x * 16;
    int ks = blockIdx.z;
    const float* Ub = Brhs;
    __shared__ float Us[64][104];
    int tid = threadIdx.x;
    int t0 = tid, t1 = tid + 256;
    int pl0 = t0 / 25, jj0 = t0 % 25;
    int pl1 = t1 / 25, jj1 = t1 % 25;
    int pidx0 = 40 + pl0 + 2;
    int jidx0 = (jj0 / 5) * 20 + pl0 + (jj0 % 5);
    int pidx1 = 40 + pl1 + 2;
    int jidx1 = (jj1 / 5) * 20 + pl1 + (jj1 % 5);
    float acc0 = 0.f, acc1 = 0.f;
    int qbeg = ks * 512, qend = qbeg + 512;
    for (int q0 = qbeg; q0 < qend; q0 += 64) {
        for (int t = tid; t < 64 * 100; t += 256) {
            int qq = t / 100, i = t % 100;
            int s = i / 20, cc = i % 20;
            int gr = r + s - 2, gc = c0 - 2 + cc;
            float v = 0.f;
            if (gr >= 0 && gr < 64 && gc >= 0 && gc < 64)
                v = Ub[(size_t)(q0 + qq) * LDB + gr * 64 + gc];
            Us[qq][i] = v;
        }
        __syncthreads();
        #pragma unroll 8
        for (int kk = 0; kk < 64; ++kk) {
            acc0 += Us[kk][pidx0] * Us[kk][jidx0];
            if (t1 < 400) acc1 += Us[kk][pidx1] * Us[kk][jidx1];
        }
        __syncthreads();
    }
    {
        int p = r * 64 + c0 + pl0;
        atomicAdd(&covAcc[(size_t)jj0 * NPT + p], acc0);
    }
    if (t1 < 400) {
        int p = r * 64 + c0 + pl1;
        atomicAdd(&covAcc[(size_t)jj1 * NPT + p], acc1);
    }
}

// ------------- cov_finish: out = valid ? tmpX - covAcc : 0 -------------
__global__ __launch_bounds__(256) void cov_finish_kernel(const float* __restrict__ tmpX,
                                                         const float* __restrict__ covAcc,
                                                         float* __restrict__ out, int bofs) {
    int e = blockIdx.x * 256 + threadIdx.x;   // 0 .. 102399
    int jj = e >> 12, p = e & 4095;
    int r = p >> 6, c = p & 63;
    int qr = r + jj / 5 - 2, qc = c + jj % 5 - 2;
    float v = 0.f;
    if (qr >= 0 && qr < 64 && qc >= 0 && qc < 64)
        v = tmpX[e] - covAcc[e];
    out[((size_t)bofs * 89 + 64 + jj) * NPT + p] = v;
}

extern "C" void kernel_launch(void* const* d_in, const int* in_sizes, int n_in,
                              void* d_out, int out_size, void* d_ws, size_t ws_size,
                              hipStream_t stream) {
    (void)in_sizes; (void)n_in; (void)out_size;
    const float* x  = (const float*)d_in[0];
    const float* y  = (const float*)d_in[1];
    const float* pw = (const float*)d_in[2];
    const float* pb = (const float*)d_in[3];
    float* out = (float*)d_out;
    float* ws  = (float*)d_ws;

    const size_t SZ_B = (size_t)NPT * LDB;
    const size_t NEED1 = 2 * APSTR + SZ_B + 2 * ILSTR + 4 * NPT + (size_t)NPT * CCH;
    const size_t NEED2 = NEED1 + SZ_B;
    if (ws_size < NEED1 * sizeof(float)) return;
    int twoB = (ws_size >= NEED2 * sizeof(float)) ? 1 : 0;

    float* AmatP = ws;
    float* Brhs  = AmatP + 2 * APSTR;
    float* invL  = Brhs + (size_t)(twoB ? 2 : 1) * SZ_B;
    float* nx    = invL + 2 * ILSTR;
    float* ny    = nx + 2 * NPT;
    float* ysBuf = ny + 2 * NPT;
    ushort_t* ysH = (ushort_t*)ysBuf;
    ushort_t* ysL = ysH + (size_t)NPT * CCH;

    norms_kernel<<<dim3(16, 2), 256, 0, stream>>>(x, nx, 0);
    norms_kernel<<<dim3(16, 2), 256, 0, stream>>>(y, ny, 0);

    // K_yy grams -> packed lower Amat
    for (int b = 0; b < 2; ++b) {
        split_kernel<<<dim3(8, 64, 1), 256, 0, stream>>>(y, ysH, ysL, b);
        gramA_packed_kernel<<<dim3(32, 32, 1), 256, 0, stream>>>(
            ysH, ysL, ny + (size_t)b * NPT, AmatP + (size_t)b * APSTR);
    }

    // blocked cholesky, both batches (z=2): trsm'd panels + fused potf2 in syrk
    potf2_packed_kernel<<<dim3(1, 1, 2), 256, 0, stream>>>(AmatP, invL, 0);
    for (int kb = 0; kb < NKB - 1; ++kb) {
        int nt = NKB - 1 - kb;
        trsm_packed_kernel<<<dim3(nt, 1, 2), 256, 0, stream>>>(AmatP, invL, kb);
        syrk_fact_packed_kernel<<<dim3(nt, nt, 2), 256, 0, stream>>>(AmatP, invL, kb);
    }

    if (twoB) {
        for (int b = 0; b < 2; ++b) {
            split_kernel<<<dim3(8, 64, 1), 256, 0, stream>>>(y, ysH, ysL, b);
            features_kernel<<<dim3(1024, 1), 256, 0, stream>>>(pw, pb, Brhs + (size_t)b * SZ_B);
            gramX_kernel<<<dim3(32, 32, 1), 256, 0, stream>>>(
                ysH, ysL, x + (size_t)b * CCH * NPT, ny + (size_t)b * NPT, nx + (size_t)b * NPT,
                Brhs + (size_t)b * SZ_B);
        }
        trsm_rhs_kernel<<<dim3(65, 1, 2), 256, 0, stream>>>(Brhs, invL, SZ_B);
        for (int kb = 0; kb < NKB - 1; ++kb) {
            solve_step_kernel<<<dim3(65, NKB - 1 - kb, 2), 256, 0, stream>>>(
                AmatP, Brhs, invL, SZ_B, kb);
        }
        for (int b = 0; b < 2; ++b) {
            float* Bb = Brhs + (size_t)b * SZ_B;
            float* covAcc = invL + (size_t)b * ILSTR;          // invL dead after solve
            float* tmpX   = covAcc + (size_t)25 * NPT;
            zero_kernel<<<dim3(400), 256, 0, stream>>>(covAcc, 25 * NPT);
            mu_kernel<<<dim3(64, 1, 1), 256, 0, stream>>>(Bb, out, b);
            kxx_local_kernel<<<dim3(4, 64, 1), 256, 0, stream>>>(x, nx + (size_t)b * NPT, tmpX, b);
            cov_part_kernel<<<dim3(4, 64, 8), 256, 0, stream>>>(Bb, covAcc);
            cov_finish_kernel<<<dim3(400), 256, 0, stream>>>(tmpX, covAcc, out, b);
        }
    } else {
        for (int b = 0; b < 2; ++b) {
            split_kernel<<<dim3(8, 64, 1), 256, 0, stream>>>(y, ysH, ysL, b);
            features_kernel<<<dim3(1024, 1), 256, 0, stream>>>(pw, pb, Brhs);
            gramX_kernel<<<dim3(32, 32, 1), 256, 0, stream>>>(
                ysH, ysL, x + (size_t)b * CCH * NPT, ny + (size_t)b * NPT, nx + (size_t)b * NPT, Brhs);
            trsm_rhs_kernel<<<dim3(65, 1, 1), 256, 0, stream>>>(Brhs, invL + (size_t)b * ILSTR, 0);
            for (int kb = 0; kb < NKB - 1; ++kb) {
                solve_step_kernel<<<dim3(65, NKB - 1 - kb, 1), 256, 0, stream>>>(
                    AmatP + (size_t)b * APSTR, Brhs, invL + (size_t)b * ILSTR, 0, kb);
            }
            // this batch's invL slot is dead now; other slot still live for b=1
            float* covAcc = invL + (size_t)b * ILSTR;
            float* tmpX   = covAcc + (size_t)25 * NPT;
            zero_kernel<<<dim3(400), 256, 0, stream>>>(covAcc, 25 * NPT);
            mu_kernel<<<dim3(64, 1, 1), 256, 0, stream>>>(Brhs, out, b);
            kxx_local_kernel<<<dim3(4, 64, 1), 256, 0, stream>>>(x, nx + (size_t)b * NPT, tmpX, b);
            cov_part_kernel<<<dim3(4, 64, 8), 256, 0, stream>>>(Brhs, covAcc);
            cov_finish_kernel<<<dim3(400), 256, 0, stream>>>(tmpX, covAcc, out, b);
        }
    }
}